// Round 3
// baseline (586.914 us; speedup 1.0000x reference)
//
#include <hip/hip_runtime.h>
#include <math.h>

#define ATT_SCALE 0.17677669529663687f  // 32^-0.5

typedef __bf16 bf16x8 __attribute__((ext_vector_type(8)));
typedef __bf16 bf16x4 __attribute__((ext_vector_type(4)));
typedef float  f32x4  __attribute__((ext_vector_type(4)));

#define MFMA16(a,b,c) __builtin_amdgcn_mfma_f32_16x16x32_bf16(a,b,c,0,0,0)

// ws layout: [0,786432) f32 expanded bias; then bf16 swizzled weights
#define BIAS_BYTES 786432
#define WKV_OFF 0        // 192x384  kt6  NRT24
#define WQ_OFF  73728    // 96x192   kt3  NRT12 (pre-scaled)
#define WP_OFF  92160    // 192x96   kt6  NRT6
#define WD_OFF  110592   // 192x768  kt6  NRT48
#define W1_OFF  258048   // 96x384   kt3  NRT24
#define W2_OFF  294912   // 384x96   kt12 NRT6
#define NSWZ    331776

static __device__ __forceinline__ float gelu_exact(float v){
    return 0.5f * v * (1.0f + erff(v * 0.70710678118654752f));
}

static __device__ __forceinline__ bf16x8 afrag(const __bf16* w, int NRT, int kt, int rt, int lane){
    return ((const bf16x8*)w)[(kt*NRT + rt)*64 + lane];
}

// ---------------- prep: bias expand + weight bf16 swizzle ----------------
__global__ __launch_bounds__(256) void k_prep(const float* __restrict__ table,
    const float* __restrict__ Wkv, const float* __restrict__ Wq,
    const float* __restrict__ Wp,  const float* __restrict__ Wd,
    const float* __restrict__ W1,  const float* __restrict__ W2,
    float* __restrict__ bias, __bf16* __restrict__ wsw){
    int id = blockIdx.x * 256 + threadIdx.x;
    if (id < 196608){
        int k  = id & 63;
        int qg = (id >> 6) & 511;
        int h  = id >> 15;
        int qi = qg >> 6, qj = (qg >> 3) & 7, qk = qg & 7;
        int ki = k >> 4,  kj = (k >> 2) & 3,  kk = k & 3;
        int r0 = (qi >> 1) - ki + 3;
        int r1 = (qj >> 1) - kj + 3;
        int r2 = (qk >> 1) - kk + 3;
        bias[id] = table[((r0 * 7 + r1) * 7 + r2) * 6 + h];
        return;
    }
    id -= 196608;
    if (id >= NSWZ) return;
    const float* W; int N, NRT, off; float sc = 1.f;
    if      (id < WQ_OFF){ W = Wkv; N = 384; NRT = 24; off = WKV_OFF; }
    else if (id < WP_OFF){ W = Wq;  N = 192; NRT = 12; off = WQ_OFF; sc = ATT_SCALE; }
    else if (id < WD_OFF){ W = Wp;  N = 96;  NRT = 6;  off = WP_OFF; }
    else if (id < W1_OFF){ W = Wd;  N = 768; NRT = 48; off = WD_OFF; }
    else if (id < W2_OFF){ W = W1;  N = 384; NRT = 24; off = W1_OFF; }
    else                 { W = W2;  N = 96;  NRT = 6;  off = W2_OFF; }
    int lid  = id - off;
    int j    = lid & 7, lane = (lid >> 3) & 63, tile = lid >> 9;
    int rt   = tile % NRT, kt = tile / NRT;
    int n    = rt * 16 + (lane & 15);
    int k    = kt * 32 + (lane >> 4) * 8 + j;
    wsw[id + 0] = (__bf16)(W[k * N + n] * sc);
}

// ---------------- deconv path (MFMA): d_out = sc (full overwrite) ----------------
__global__ __launch_bounds__(512) void k_deconv(const float* __restrict__ x,
    const float* __restrict__ eg, const float* __restrict__ eb,
    const __bf16* __restrict__ wsw, const float* __restrict__ db,
    float* __restrict__ out){
    __shared__ __bf16 xe[64][200];
    const int tid = threadIdx.x, lane = tid & 63, w = tid >> 6;
    const int ci0 = blockIdx.x * 64;
    {   // LN stage -> bf16
        int row = tid >> 3, sub = tid & 7;
        const float* xp = x + (ci0 + row) * 192 + sub * 24;
        float v[24]; float s = 0.f, ss = 0.f;
        #pragma unroll
        for (int i = 0; i < 6; i++){
            float4 t = ((const float4*)xp)[i];
            v[4*i] = t.x; v[4*i+1] = t.y; v[4*i+2] = t.z; v[4*i+3] = t.w;
            s += t.x + t.y + t.z + t.w;
            ss += t.x*t.x + t.y*t.y + t.z*t.z + t.w*t.w;
        }
        #pragma unroll
        for (int m = 1; m < 8; m <<= 1){ s += __shfl_xor(s, m); ss += __shfl_xor(ss, m); }
        float mu = s * (1.f/192.f), var = ss * (1.f/192.f) - mu*mu, rs = rsqrtf(var + 1e-5f);
        #pragma unroll
        for (int i = 0; i < 3; i++){
            bf16x8 t;
            #pragma unroll
            for (int jj = 0; jj < 8; jj++){
                int c = sub*24 + 8*i + jj;
                t[jj] = (__bf16)((v[8*i+jj] - mu) * rs * eg[c] + eb[c]);
            }
            *(bf16x8*)&xe[row][sub*24 + 8*i] = t;
        }
    }
    __syncthreads();
    const int ct = w & 3, rh = w >> 2;
    const int tok = ct * 16 + (lane & 15);
    const int ci  = ci0 + tok;
    const int bb  = ci >> 14, rem = ci & 16383;
    const int sC  = rem >> 10, hC = (rem >> 5) & 31, wC = rem & 31;
    const int ftb = ((bb * 32 + 2 * sC) * 64 + 2 * hC) * 64 + 2 * wC;
    bf16x8 bfr[6];
    #pragma unroll
    for (int kt = 0; kt < 6; kt++) bfr[kt] = *(const bf16x8*)&xe[tok][kt*32 + (lane>>4)*8];
    for (int i = 0; i < 24; i++){
        int rt = rh * 24 + i;
        f32x4 acc = {0.f,0.f,0.f,0.f};
        #pragma unroll
        for (int kt = 0; kt < 6; kt++) acc = MFMA16(afrag(wsw + WD_OFF, 48, kt, rt, lane), bfr[kt], acc);
        int nb = rt * 16 + ((lane >> 4) << 2);
        int o = nb >> 3, ij0 = nb & 7;
        float bo = db[o];
        #pragma unroll
        for (int r = 0; r < 4; r++){
            int ijk = ij0 + r;
            int ft = ftb + (ijk >> 2) * 4096 + ((ijk >> 1) & 1) * 64 + (ijk & 1);
            out[ft * 96 + o] = acc[r] + bo;
        }
    }
}

// ---------------- fused windowed cross-attention (MFMA): d_out += attn ----------------
// LDS 74.5 KB -> 2 blocks/CU; P redistribution via ds_bpermute (no Pw buffer).
__global__ __launch_bounds__(512, 4) void k_attn(const float* __restrict__ x,
    const float* __restrict__ xd, const float* __restrict__ g1, const float* __restrict__ b1v,
    const float* __restrict__ bkv, const float* __restrict__ bq, const float* __restrict__ bpj,
    const __bf16* __restrict__ wsw, const float* __restrict__ bias, float* __restrict__ yout){
    __shared__ __bf16 Qs[64][196];   // xln -> Q -> attn-out (aliased phases)
    __shared__ __bf16 Ks[64][196];
    __shared__ __bf16 Vt[192][68];   // V transposed [d][kv]
    const int tid = threadIdx.x, lane = tid & 63, w = tid >> 6;
    const int win = blockIdx.x, b = win >> 8, wrem = win & 255;
    const int sw_ = wrem >> 6, hw_ = (wrem >> 3) & 7, ww_ = wrem & 7;

    {   // LN stage of coarse x window -> Qs (as xln)
        int row = tid >> 3, sub = tid & 7;
        int si = row >> 4, hi = (row >> 2) & 3, wi = row & 3;
        int ci = ((b * 16 + 4 * sw_ + si) * 32 + 4 * hw_ + hi) * 32 + 4 * ww_ + wi;
        const float* xp = x + ci * 192 + sub * 24;
        float v[24]; float s = 0.f, ss = 0.f;
        #pragma unroll
        for (int i = 0; i < 6; i++){
            float4 t = ((const float4*)xp)[i];
            v[4*i] = t.x; v[4*i+1] = t.y; v[4*i+2] = t.z; v[4*i+3] = t.w;
            s += t.x + t.y + t.z + t.w;
            ss += t.x*t.x + t.y*t.y + t.z*t.z + t.w*t.w;
        }
        #pragma unroll
        for (int m = 1; m < 8; m <<= 1){ s += __shfl_xor(s, m); ss += __shfl_xor(ss, m); }
        float mu = s * (1.f/192.f), var = ss * (1.f/192.f) - mu*mu, rs = rsqrtf(var + 1e-5f);
        #pragma unroll
        for (int i = 0; i < 3; i++){
            bf16x8 t;
            #pragma unroll
            for (int jj = 0; jj < 8; jj++){
                int c = sub*24 + 8*i + jj;
                t[jj] = (__bf16)((v[8*i+jj] - mu) * rs * g1[c] + b1v[c]);
            }
            *(bf16x8*)&Qs[row][sub*24 + 8*i] = t;
        }
    }
    __syncthreads();
    {   // KVproj: KV^T = Wkv^T @ xln^T ; waves 0-3 -> K rows, 4-7 -> V^T
        const int ct = w & 3, rh = w >> 2;
        const int tok = ct * 16 + (lane & 15);
        bf16x8 bfr[6];
        #pragma unroll
        for (int kt = 0; kt < 6; kt++) bfr[kt] = *(const bf16x8*)&Qs[tok][kt*32 + (lane>>4)*8];
        #pragma unroll
        for (int i = 0; i < 12; i++){
            int rt = rh * 12 + i;
            f32x4 acc = {0.f,0.f,0.f,0.f};
            #pragma unroll
            for (int kt = 0; kt < 6; kt++) acc = MFMA16(afrag(wsw + WKV_OFF, 24, kt, rt, lane), bfr[kt], acc);
            int cb = rt * 16 + ((lane >> 4) << 2);
            float4 b4 = *(const float4*)&bkv[cb];
            acc[0] += b4.x; acc[1] += b4.y; acc[2] += b4.z; acc[3] += b4.w;
            if (cb < 192){
                bf16x4 t;
                #pragma unroll
                for (int r = 0; r < 4; r++) t[r] = (__bf16)acc[r];
                *(bf16x4*)&Ks[tok][cb] = t;
            } else {
                #pragma unroll
                for (int r = 0; r < 4; r++) Vt[cb - 192 + r][tok] = (__bf16)acc[r];
            }
        }
    }
    __syncthreads();

    const int li_ = lane & 15, gt_ = lane >> 4, rsel = lane >> 5;

    for (int qt = 0; qt < 8; qt++){
        {   // Qproj: Q^T = Wq^T(scaled) @ xd^T ; B-frags straight from global f32
            const int ct = w & 3, rh = w >> 2;
            const int ql = ct * 16 + (lane & 15);
            const int ft = ((b * 32 + 8 * sw_ + qt) * 64 + 8 * hw_ + (ql >> 3)) * 64 + 8 * ww_ + (ql & 7);
            bf16x8 bfr[3];
            #pragma unroll
            for (int kt = 0; kt < 3; kt++){
                const float* xp = xd + ft * 96 + kt * 32 + (lane >> 4) * 8;
                float4 t0 = *(const float4*)xp;
                float4 t1 = *(const float4*)(xp + 4);
                bf16x8 t;
                t[0]=(__bf16)t0.x; t[1]=(__bf16)t0.y; t[2]=(__bf16)t0.z; t[3]=(__bf16)t0.w;
                t[4]=(__bf16)t1.x; t[5]=(__bf16)t1.y; t[6]=(__bf16)t1.z; t[7]=(__bf16)t1.w;
                bfr[kt] = t;
            }
            #pragma unroll
            for (int i = 0; i < 6; i++){
                int rt = rh * 6 + i;
                f32x4 acc = {0.f,0.f,0.f,0.f};
                #pragma unroll
                for (int kt = 0; kt < 3; kt++) acc = MFMA16(afrag(wsw + WQ_OFF, 12, kt, rt, lane), bfr[kt], acc);
                int cb = rt * 16 + ((lane >> 4) << 2);
                float4 b4 = *(const float4*)&bq[cb];
                bf16x4 t;
                t[0] = (__bf16)(acc[0] + b4.x * ATT_SCALE);
                t[1] = (__bf16)(acc[1] + b4.y * ATT_SCALE);
                t[2] = (__bf16)(acc[2] + b4.z * ATT_SCALE);
                t[3] = (__bf16)(acc[3] + b4.w * ATT_SCALE);
                *(bf16x4*)&Qs[ql][cb] = t;
            }
        }
        __syncthreads();
        // scores + softmax + in-register P redistribution + PV
        f32x4 ov[3][2];
        #pragma unroll
        for (int ui = 0; ui < 3; ui++){
            const int u = w * 3 + ui;
            const int h = u >> 2, qct = u & 3;
            f32x4 sc[4];
            __builtin_amdgcn_s_setprio(1);
            #pragma unroll
            for (int rt = 0; rt < 4; rt++){
                bf16x8 a  = *(const bf16x8*)&Ks[rt*16 + li_][h*32 + gt_*8];
                bf16x8 bq8 = *(const bf16x8*)&Qs[qct*16 + li_][h*32 + gt_*8];
                f32x4 z = {0.f,0.f,0.f,0.f};
                sc[rt] = MFMA16(a, bq8, z);
            }
            __builtin_amdgcn_s_setprio(0);
            const int qg = qt * 64 + qct * 16 + li_;
            const float* bp = bias + (h * 512 + qg) * 64 + (gt_ << 2);
            #pragma unroll
            for (int rt = 0; rt < 4; rt++){
                float4 b4 = *(const float4*)(bp + rt * 16);
                sc[rt][0] += b4.x; sc[rt][1] += b4.y; sc[rt][2] += b4.z; sc[rt][3] += b4.w;
            }
            float m = sc[0][0];
            #pragma unroll
            for (int rt = 0; rt < 4; rt++)
                #pragma unroll
                for (int r = 0; r < 4; r++) m = fmaxf(m, sc[rt][r]);
            m = fmaxf(m, __shfl_xor(m, 16));
            m = fmaxf(m, __shfl_xor(m, 32));
            float sum = 0.f;
            #pragma unroll
            for (int rt = 0; rt < 4; rt++)
                #pragma unroll
                for (int r = 0; r < 4; r++){ float e = __expf(sc[rt][r] - m); sc[rt][r] = e; sum += e; }
            sum += __shfl_xor(sum, 16);
            sum += __shfl_xor(sum, 32);
            float inv = 1.f / sum;
            // pack normalized P into bf16 pair words: pwv[rt][h2] covers kv = rt*16+gt*4+2*h2+{0,1}
            unsigned pwv[4][2];
            #pragma unroll
            for (int rt = 0; rt < 4; rt++){
                union { __bf16 hh[2]; unsigned u; } c0, c1;
                c0.hh[0] = (__bf16)(sc[rt][0] * inv); c0.hh[1] = (__bf16)(sc[rt][1] * inv);
                c1.hh[0] = (__bf16)(sc[rt][2] * inv); c1.hh[1] = (__bf16)(sc[rt][3] * inv);
                pwv[rt][0] = c0.u; pwv[rt][1] = c1.u;
            }
            // redistribute C-frag -> B-frag layout: word t of kt comes from lane gs*16+li,
            // tile rt_s = 2kt + rsel, pair h2 = t&1, gs = 2*(gt&1) + (t>>1)
            unsigned bfw[2][4];
            #pragma unroll
            for (int kt = 0; kt < 2; kt++){
                #pragma unroll
                for (int t = 0; t < 4; t++){
                    int gs   = ((gt_ & 1) << 1) + (t >> 1);
                    int addr = (((gs << 4) + li_) << 2);
                    int w0 = __builtin_amdgcn_ds_bpermute(addr, (int)pwv[2*kt + 0][t & 1]);
                    int w1 = __builtin_amdgcn_ds_bpermute(addr, (int)pwv[2*kt + 1][t & 1]);
                    bfw[kt][t] = rsel ? (unsigned)w1 : (unsigned)w0;
                }
            }
            union { unsigned u[4]; bf16x8 v; } pb0, pb1;
            #pragma unroll
            for (int t = 0; t < 4; t++){ pb0.u[t] = bfw[0][t]; pb1.u[t] = bfw[1][t]; }
            __builtin_amdgcn_s_setprio(1);
            #pragma unroll
            for (int dt = 0; dt < 2; dt++){
                f32x4 o = {0.f,0.f,0.f,0.f};
                bf16x8 a0 = *(const bf16x8*)&Vt[h*32 + dt*16 + li_][gt_*8];
                bf16x8 a1 = *(const bf16x8*)&Vt[h*32 + dt*16 + li_][32 + gt_*8];
                o = MFMA16(a0, pb0.v, o);
                o = MFMA16(a1, pb1.v, o);
                ov[ui][dt] = o;
            }
            __builtin_amdgcn_s_setprio(0);
        }
        __syncthreads();   // all Qs reads done
        #pragma unroll
        for (int ui = 0; ui < 3; ui++){
            const int u = w * 3 + ui;
            const int h = u >> 2, qct = u & 3;
            const int tok = qct * 16 + li_;
            #pragma unroll
            for (int dt = 0; dt < 2; dt++){
                int cb = h * 32 + dt * 16 + (gt_ << 2);
                bf16x4 t;
                #pragma unroll
                for (int r = 0; r < 4; r++) t[r] = (__bf16)ov[ui][dt][r];
                *(bf16x4*)&Qs[tok][cb] = t;
            }
        }
        __syncthreads();
        {   // outproj: Y^T = Wp^T @ out^T ; += into d_out (y = sc + attn)
            const int ct = w & 3, rh = w >> 2;
            const int ql = ct * 16 + (lane & 15);
            const int ft = ((b * 32 + 8 * sw_ + qt) * 64 + 8 * hw_ + (ql >> 3)) * 64 + 8 * ww_ + (ql & 7);
            bf16x8 bfr[6];
            #pragma unroll
            for (int kt = 0; kt < 6; kt++) bfr[kt] = *(const bf16x8*)&Qs[ql][kt*32 + (lane>>4)*8];
            #pragma unroll
            for (int i = 0; i < 3; i++){
                int rt = rh * 3 + i;
                f32x4 acc = {0.f,0.f,0.f,0.f};
                #pragma unroll
                for (int kt = 0; kt < 6; kt++) acc = MFMA16(afrag(wsw + WP_OFF, 6, kt, rt, lane), bfr[kt], acc);
                int cb = rt * 16 + ((lane >> 4) << 2);
                float4 b4 = *(const float4*)&bpj[cb];
                float4 old = *(const float4*)&yout[ft * 96 + cb];
                float4 res;
                res.x = old.x + acc[0] + b4.x;
                res.y = old.y + acc[1] + b4.y;
                res.z = old.z + acc[2] + b4.z;
                res.w = old.w + acc[3] + b4.w;
                *(float4*)&yout[ft * 96 + cb] = res;
            }
        }
        __syncthreads();   // before next qt overwrites Qs
    }
}

// ---------------- MLP (MFMA): d_out = y + W2(gelu(W1 ln(y)+b1))+b2, in place ----------------
__global__ __launch_bounds__(512, 4) void k_mlp(const float* __restrict__ y,
    const float* __restrict__ g2, const float* __restrict__ b2v,
    const __bf16* __restrict__ wsw, const float* __restrict__ b1m,
    const float* __restrict__ b2m, float* __restrict__ outp){
    __shared__ __bf16 yln[64][104];
    __shared__ __bf16 hsm[64][392];
    __shared__ __bf16 ybf[64][96];    // raw y stash for residual (saves 101MB global re-read)
    const int tid = threadIdx.x, lane = tid & 63, w = tid >> 6;
    const int t0 = blockIdx.x * 64;
    {   // LN stage
        int row = tid >> 3, sub = tid & 7;
        const float* yp = y + (t0 + row) * 96 + sub * 12;
        float v[12]; float s = 0.f, ss = 0.f;
        #pragma unroll
        for (int i = 0; i < 3; i++){
            float4 t = ((const float4*)yp)[i];
            v[4*i] = t.x; v[4*i+1] = t.y; v[4*i+2] = t.z; v[4*i+3] = t.w;
            s += t.x + t.y + t.z + t.w;
            ss += t.x*t.x + t.y*t.y + t.z*t.z + t.w*t.w;
        }
        #pragma unroll
        for (int i = 0; i < 3; i++){
            bf16x4 t;
            #pragma unroll
            for (int jj = 0; jj < 4; jj++) t[jj] = (__bf16)v[4*i+jj];
            *(bf16x4*)&ybf[row][sub*12 + 4*i] = t;
        }
        #pragma unroll
        for (int m = 1; m < 8; m <<= 1){ s += __shfl_xor(s, m); ss += __shfl_xor(ss, m); }
        float mu = s * (1.f/96.f), var = ss * (1.f/96.f) - mu*mu, rs = rsqrtf(var + 1e-5f);
        #pragma unroll
        for (int i = 0; i < 3; i++){
            bf16x4 t;
            #pragma unroll
            for (int jj = 0; jj < 4; jj++){
                int c = sub*12 + 4*i + jj;
                t[jj] = (__bf16)((v[4*i+jj] - mu) * rs * g2[c] + b2v[c]);
            }
            *(bf16x4*)&yln[row][sub*12 + 4*i] = t;
        }
    }
    __syncthreads();
    const int ct = w & 3, rh = w >> 2;
    const int tok = ct * 16 + (lane & 15);
    {   // GEMM1: h^T = W1^T @ yln^T, gelu -> hsm row-major
        bf16x8 bfr[3];
        #pragma unroll
        for (int kt = 0; kt < 3; kt++) bfr[kt] = *(const bf16x8*)&yln[tok][kt*32 + (lane>>4)*8];
        #pragma unroll
        for (int i = 0; i < 12; i++){
            int rt = rh * 12 + i;
            f32x4 acc = {0.f,0.f,0.f,0.f};
            #pragma unroll
            for (int kt = 0; kt < 3; kt++) acc = MFMA16(afrag(wsw + W1_OFF, 24, kt, rt, lane), bfr[kt], acc);
            int cb = rt * 16 + ((lane >> 4) << 2);
            float4 b4 = *(const float4*)&b1m[cb];
            bf16x4 t;
            t[0] = (__bf16)gelu_exact(acc[0] + b4.x);
            t[1] = (__bf16)gelu_exact(acc[1] + b4.y);
            t[2] = (__bf16)gelu_exact(acc[2] + b4.z);
            t[3] = (__bf16)gelu_exact(acc[3] + b4.w);
            *(bf16x4*)&hsm[tok][cb] = t;
        }
    }
    __syncthreads();
    {   // GEMM2: o^T = W2^T @ h^T ; residual add from LDS stash, in-place
        bf16x8 bfr[12];
        #pragma unroll
        for (int kt = 0; kt < 12; kt++) bfr[kt] = *(const bf16x8*)&hsm[tok][kt*32 + (lane>>4)*8];
        #pragma unroll
        for (int i = 0; i < 3; i++){
            int rt = rh * 3 + i;
            f32x4 acc = {0.f,0.f,0.f,0.f};
            #pragma unroll
            for (int kt = 0; kt < 12; kt++) acc = MFMA16(afrag(wsw + W2_OFF, 6, kt, rt, lane), bfr[kt], acc);
            int cb = rt * 16 + ((lane >> 4) << 2);
            float4 b4 = *(const float4*)&b2m[cb];
            bf16x4 yv = *(const bf16x4*)&ybf[tok][cb];
            float4 res;
            res.x = (float)yv[0] + acc[0] + b4.x;
            res.y = (float)yv[1] + acc[1] + b4.y;
            res.z = (float)yv[2] + acc[2] + b4.z;
            res.w = (float)yv[3] + acc[3] + b4.w;
            *(float4*)&outp[(t0 + tok) * 96 + cb] = res;
        }
    }
}

extern "C" void kernel_launch(void* const* d_in, const int* in_sizes, int n_in,
                              void* d_out, int out_size, void* d_ws, size_t ws_size,
                              hipStream_t stream){
    const float* x    = (const float*)d_in[0];
    const float* xd   = (const float*)d_in[1];
    const float* g1   = (const float*)d_in[2];
    const float* b1v  = (const float*)d_in[3];
    const float* Wkv  = (const float*)d_in[4];
    const float* bkv  = (const float*)d_in[5];
    const float* Wq   = (const float*)d_in[6];
    const float* bq   = (const float*)d_in[7];
    const float* Wp   = (const float*)d_in[8];
    const float* bpj  = (const float*)d_in[9];
    const float* btab = (const float*)d_in[10];
    const float* eg   = (const float*)d_in[11];
    const float* eb   = (const float*)d_in[12];
    const float* dw   = (const float*)d_in[13];
    const float* db   = (const float*)d_in[14];
    const float* g2   = (const float*)d_in[15];
    const float* b2v  = (const float*)d_in[16];
    const float* W1   = (const float*)d_in[17];
    const float* b1m  = (const float*)d_in[18];
    const float* W2   = (const float*)d_in[19];
    const float* b2m  = (const float*)d_in[20];
    (void)in_sizes; (void)n_in; (void)out_size; (void)ws_size;

    float*   out  = (float*)d_out;
    float*   bias = (float*)d_ws;
    __bf16*  wsw  = (__bf16*)((char*)d_ws + BIAS_BYTES);

    k_prep  <<<2064, 256, 0, stream>>>(btab, Wkv, Wq, Wp, dw, W1, W2, bias, wsw);
    k_deconv<<<512, 512, 0, stream>>>(x, eg, eb, wsw, db, out);
    k_attn  <<<512, 512, 0, stream>>>(x, xd, g1, b1v, bkv, bq, bpj, wsw, bias, out);
    k_mlp   <<<4096, 512, 0, stream>>>(out, g2, b2v, wsw, b1m, b2m, out);
}

// Round 4
// 385.108 us; speedup vs baseline: 1.5240x; 1.5240x over previous
//
#include <hip/hip_runtime.h>
#include <math.h>

#define ATT_SCALE 0.17677669529663687f  // 32^-0.5

typedef __bf16 bf16x8 __attribute__((ext_vector_type(8)));
typedef __bf16 bf16x4 __attribute__((ext_vector_type(4)));
typedef float  f32x4  __attribute__((ext_vector_type(4)));

#define MFMA16(a,b,c) __builtin_amdgcn_mfma_f32_16x16x32_bf16(a,b,c,0,0,0)

// ws layout: [0,786432) f32 expanded bias; then bf16 swizzled weights
#define BIAS_BYTES 786432
#define WKV_OFF 0        // 192x384  kt6  NRT24
#define WQ_OFF  73728    // 96x192   kt3  NRT12 (pre-scaled)
#define WP_OFF  92160    // 192x96   kt6  NRT6
#define WD_OFF  110592   // 192x768  kt6  NRT48
#define W1_OFF  258048   // 96x384   kt3  NRT24
#define W2_OFF  294912   // 384x96   kt12 NRT6
#define NSWZ    331776

static __device__ __forceinline__ float gelu_exact(float v){
    return 0.5f * v * (1.0f + erff(v * 0.70710678118654752f));
}

static __device__ __forceinline__ bf16x8 afrag(const __bf16* w, int NRT, int kt, int rt, int lane){
    return ((const bf16x8*)w)[(kt*NRT + rt)*64 + lane];
}

// ---------------- prep: bias expand + weight bf16 swizzle ----------------
__global__ __launch_bounds__(256) void k_prep(const float* __restrict__ table,
    const float* __restrict__ Wkv, const float* __restrict__ Wq,
    const float* __restrict__ Wp,  const float* __restrict__ Wd,
    const float* __restrict__ W1,  const float* __restrict__ W2,
    float* __restrict__ bias, __bf16* __restrict__ wsw){
    int id = blockIdx.x * 256 + threadIdx.x;
    if (id < 196608){
        int k  = id & 63;
        int qg = (id >> 6) & 511;
        int h  = id >> 15;
        int qi = qg >> 6, qj = (qg >> 3) & 7, qk = qg & 7;
        int ki = k >> 4,  kj = (k >> 2) & 3,  kk = k & 3;
        int r0 = (qi >> 1) - ki + 3;
        int r1 = (qj >> 1) - kj + 3;
        int r2 = (qk >> 1) - kk + 3;
        bias[id] = table[((r0 * 7 + r1) * 7 + r2) * 6 + h];
        return;
    }
    id -= 196608;
    if (id >= NSWZ) return;
    const float* W; int N, NRT, off; float sc = 1.f;
    if      (id < WQ_OFF){ W = Wkv; N = 384; NRT = 24; off = WKV_OFF; }
    else if (id < WP_OFF){ W = Wq;  N = 192; NRT = 12; off = WQ_OFF; sc = ATT_SCALE; }
    else if (id < WD_OFF){ W = Wp;  N = 96;  NRT = 6;  off = WP_OFF; }
    else if (id < W1_OFF){ W = Wd;  N = 768; NRT = 48; off = WD_OFF; }
    else if (id < W2_OFF){ W = W1;  N = 384; NRT = 24; off = W1_OFF; }
    else                 { W = W2;  N = 96;  NRT = 6;  off = W2_OFF; }
    int lid  = id - off;
    int j    = lid & 7, lane = (lid >> 3) & 63, tile = lid >> 9;
    int rt   = tile % NRT, kt = tile / NRT;
    int n    = rt * 16 + (lane & 15);
    int k    = kt * 32 + (lane >> 4) * 8 + j;
    wsw[id + 0] = (__bf16)(W[k * N + n] * sc);
}

// ---------------- deconv path (MFMA): d_out = sc (full overwrite) ----------------
__global__ __launch_bounds__(512) void k_deconv(const float* __restrict__ x,
    const float* __restrict__ eg, const float* __restrict__ eb,
    const __bf16* __restrict__ wsw, const float* __restrict__ db,
    float* __restrict__ out){
    __shared__ __bf16 xe[64][200];
    const int tid = threadIdx.x, lane = tid & 63, w = tid >> 6;
    const int ci0 = blockIdx.x * 64;
    {   // LN stage -> bf16
        int row = tid >> 3, sub = tid & 7;
        const float* xp = x + (ci0 + row) * 192 + sub * 24;
        float v[24]; float s = 0.f, ss = 0.f;
        #pragma unroll
        for (int i = 0; i < 6; i++){
            float4 t = ((const float4*)xp)[i];
            v[4*i] = t.x; v[4*i+1] = t.y; v[4*i+2] = t.z; v[4*i+3] = t.w;
            s += t.x + t.y + t.z + t.w;
            ss += t.x*t.x + t.y*t.y + t.z*t.z + t.w*t.w;
        }
        #pragma unroll
        for (int m = 1; m < 8; m <<= 1){ s += __shfl_xor(s, m); ss += __shfl_xor(ss, m); }
        float mu = s * (1.f/192.f), var = ss * (1.f/192.f) - mu*mu, rs = rsqrtf(var + 1e-5f);
        #pragma unroll
        for (int i = 0; i < 3; i++){
            bf16x8 t;
            #pragma unroll
            for (int jj = 0; jj < 8; jj++){
                int c = sub*24 + 8*i + jj;
                t[jj] = (__bf16)((v[8*i+jj] - mu) * rs * eg[c] + eb[c]);
            }
            *(bf16x8*)&xe[row][sub*24 + 8*i] = t;
        }
    }
    __syncthreads();
    const int ct = w & 3, rh = w >> 2;
    const int tok = ct * 16 + (lane & 15);
    const int ci  = ci0 + tok;
    const int bb  = ci >> 14, rem = ci & 16383;
    const int sC  = rem >> 10, hC = (rem >> 5) & 31, wC = rem & 31;
    const int ftb = ((bb * 32 + 2 * sC) * 64 + 2 * hC) * 64 + 2 * wC;
    bf16x8 bfr[6];
    #pragma unroll
    for (int kt = 0; kt < 6; kt++) bfr[kt] = *(const bf16x8*)&xe[tok][kt*32 + (lane>>4)*8];
    for (int i = 0; i < 24; i++){
        int rt = rh * 24 + i;
        f32x4 acc = {0.f,0.f,0.f,0.f};
        #pragma unroll
        for (int kt = 0; kt < 6; kt++) acc = MFMA16(afrag(wsw + WD_OFF, 48, kt, rt, lane), bfr[kt], acc);
        int nb = rt * 16 + ((lane >> 4) << 2);
        int o = nb >> 3, ij0 = nb & 7;
        float bo = db[o];
        #pragma unroll
        for (int r = 0; r < 4; r++){
            int ijk = ij0 + r;
            int ft = ftb + (ijk >> 2) * 4096 + ((ijk >> 1) & 1) * 64 + (ijk & 1);
            out[ft * 96 + o] = acc[r] + bo;
        }
    }
}

// ---------------- fused windowed cross-attention (MFMA): d_out += attn ----------------
// LDS 74.5 KB + VGPR<=128 -> 2 blocks/CU; P redistribution via ds_bpermute (no Pw buffer).
__global__ __launch_bounds__(512) void k_attn(const float* __restrict__ x,
    const float* __restrict__ xd, const float* __restrict__ g1, const float* __restrict__ b1v,
    const float* __restrict__ bkv, const float* __restrict__ bq, const float* __restrict__ bpj,
    const __bf16* __restrict__ wsw, const float* __restrict__ bias, float* __restrict__ yout){
    __shared__ __bf16 Qs[64][196];   // xln -> Q -> attn-out (aliased phases)
    __shared__ __bf16 Ks[64][196];
    __shared__ __bf16 Vt[192][68];   // V transposed [d][kv]
    const int tid = threadIdx.x, lane = tid & 63, w = tid >> 6;
    const int win = blockIdx.x, b = win >> 8, wrem = win & 255;
    const int sw_ = wrem >> 6, hw_ = (wrem >> 3) & 7, ww_ = wrem & 7;

    {   // LN stage of coarse x window -> Qs (as xln)
        int row = tid >> 3, sub = tid & 7;
        int si = row >> 4, hi = (row >> 2) & 3, wi = row & 3;
        int ci = ((b * 16 + 4 * sw_ + si) * 32 + 4 * hw_ + hi) * 32 + 4 * ww_ + wi;
        const float* xp = x + ci * 192 + sub * 24;
        float v[24]; float s = 0.f, ss = 0.f;
        #pragma unroll
        for (int i = 0; i < 6; i++){
            float4 t = ((const float4*)xp)[i];
            v[4*i] = t.x; v[4*i+1] = t.y; v[4*i+2] = t.z; v[4*i+3] = t.w;
            s += t.x + t.y + t.z + t.w;
            ss += t.x*t.x + t.y*t.y + t.z*t.z + t.w*t.w;
        }
        #pragma unroll
        for (int m = 1; m < 8; m <<= 1){ s += __shfl_xor(s, m); ss += __shfl_xor(ss, m); }
        float mu = s * (1.f/192.f), var = ss * (1.f/192.f) - mu*mu, rs = rsqrtf(var + 1e-5f);
        #pragma unroll
        for (int i = 0; i < 3; i++){
            bf16x8 t;
            #pragma unroll
            for (int jj = 0; jj < 8; jj++){
                int c = sub*24 + 8*i + jj;
                t[jj] = (__bf16)((v[8*i+jj] - mu) * rs * g1[c] + b1v[c]);
            }
            *(bf16x8*)&Qs[row][sub*24 + 8*i] = t;
        }
    }
    __syncthreads();
    {   // KVproj: KV^T = Wkv^T @ xln^T ; waves 0-3 -> K rows, 4-7 -> V^T
        const int ct = w & 3, rh = w >> 2;
        const int tok = ct * 16 + (lane & 15);
        bf16x8 bfr[6];
        #pragma unroll
        for (int kt = 0; kt < 6; kt++) bfr[kt] = *(const bf16x8*)&Qs[tok][kt*32 + (lane>>4)*8];
        #pragma unroll
        for (int i = 0; i < 12; i++){
            int rt = rh * 12 + i;
            f32x4 acc = {0.f,0.f,0.f,0.f};
            #pragma unroll
            for (int kt = 0; kt < 6; kt++) acc = MFMA16(afrag(wsw + WKV_OFF, 24, kt, rt, lane), bfr[kt], acc);
            int cb = rt * 16 + ((lane >> 4) << 2);
            float4 b4 = *(const float4*)&bkv[cb];
            acc[0] += b4.x; acc[1] += b4.y; acc[2] += b4.z; acc[3] += b4.w;
            if (cb < 192){
                bf16x4 t;
                #pragma unroll
                for (int r = 0; r < 4; r++) t[r] = (__bf16)acc[r];
                *(bf16x4*)&Ks[tok][cb] = t;
            } else {
                #pragma unroll
                for (int r = 0; r < 4; r++) Vt[cb - 192 + r][tok] = (__bf16)acc[r];
            }
        }
    }
    __syncthreads();

    const int li_ = lane & 15, gt_ = lane >> 4, rsel = lane >> 5;

    for (int qt = 0; qt < 8; qt++){
        {   // Qproj: Q^T = Wq^T(scaled) @ xd^T ; B-frags straight from global f32
            const int ct = w & 3, rh = w >> 2;
            const int ql = ct * 16 + (lane & 15);
            const int ft = ((b * 32 + 8 * sw_ + qt) * 64 + 8 * hw_ + (ql >> 3)) * 64 + 8 * ww_ + (ql & 7);
            bf16x8 bfr[3];
            #pragma unroll
            for (int kt = 0; kt < 3; kt++){
                const float* xp = xd + ft * 96 + kt * 32 + (lane >> 4) * 8;
                float4 t0 = *(const float4*)xp;
                float4 t1 = *(const float4*)(xp + 4);
                bf16x8 t;
                t[0]=(__bf16)t0.x; t[1]=(__bf16)t0.y; t[2]=(__bf16)t0.z; t[3]=(__bf16)t0.w;
                t[4]=(__bf16)t1.x; t[5]=(__bf16)t1.y; t[6]=(__bf16)t1.z; t[7]=(__bf16)t1.w;
                bfr[kt] = t;
            }
            #pragma unroll
            for (int i = 0; i < 6; i++){
                int rt = rh * 6 + i;
                f32x4 acc = {0.f,0.f,0.f,0.f};
                #pragma unroll
                for (int kt = 0; kt < 3; kt++) acc = MFMA16(afrag(wsw + WQ_OFF, 12, kt, rt, lane), bfr[kt], acc);
                int cb = rt * 16 + ((lane >> 4) << 2);
                float4 b4 = *(const float4*)&bq[cb];
                bf16x4 t;
                t[0] = (__bf16)(acc[0] + b4.x * ATT_SCALE);
                t[1] = (__bf16)(acc[1] + b4.y * ATT_SCALE);
                t[2] = (__bf16)(acc[2] + b4.z * ATT_SCALE);
                t[3] = (__bf16)(acc[3] + b4.w * ATT_SCALE);
                *(bf16x4*)&Qs[ql][cb] = t;
            }
        }
        __syncthreads();
        // scores + softmax + in-register P redistribution + PV
        f32x4 ov[3][2];
        #pragma unroll
        for (int ui = 0; ui < 3; ui++){
            const int u = w * 3 + ui;
            const int h = u >> 2, qct = u & 3;
            f32x4 sc[4];
            __builtin_amdgcn_s_setprio(1);
            #pragma unroll
            for (int rt = 0; rt < 4; rt++){
                bf16x8 a  = *(const bf16x8*)&Ks[rt*16 + li_][h*32 + gt_*8];
                bf16x8 bq8 = *(const bf16x8*)&Qs[qct*16 + li_][h*32 + gt_*8];
                f32x4 z = {0.f,0.f,0.f,0.f};
                sc[rt] = MFMA16(a, bq8, z);
            }
            __builtin_amdgcn_s_setprio(0);
            const int qg = qt * 64 + qct * 16 + li_;
            const float* bp = bias + (h * 512 + qg) * 64 + (gt_ << 2);
            #pragma unroll
            for (int rt = 0; rt < 4; rt++){
                float4 b4 = *(const float4*)(bp + rt * 16);
                sc[rt][0] += b4.x; sc[rt][1] += b4.y; sc[rt][2] += b4.z; sc[rt][3] += b4.w;
            }
            float m = sc[0][0];
            #pragma unroll
            for (int rt = 0; rt < 4; rt++)
                #pragma unroll
                for (int r = 0; r < 4; r++) m = fmaxf(m, sc[rt][r]);
            m = fmaxf(m, __shfl_xor(m, 16));
            m = fmaxf(m, __shfl_xor(m, 32));
            float sum = 0.f;
            #pragma unroll
            for (int rt = 0; rt < 4; rt++)
                #pragma unroll
                for (int r = 0; r < 4; r++){ float e = __expf(sc[rt][r] - m); sc[rt][r] = e; sum += e; }
            sum += __shfl_xor(sum, 16);
            sum += __shfl_xor(sum, 32);
            float inv = 1.f / sum;
            // pack normalized P into bf16 pair words: pwv[rt][h2] covers kv = rt*16+gt*4+2*h2+{0,1}
            unsigned pwv[4][2];
            #pragma unroll
            for (int rt = 0; rt < 4; rt++){
                union { __bf16 hh[2]; unsigned u; } c0, c1;
                c0.hh[0] = (__bf16)(sc[rt][0] * inv); c0.hh[1] = (__bf16)(sc[rt][1] * inv);
                c1.hh[0] = (__bf16)(sc[rt][2] * inv); c1.hh[1] = (__bf16)(sc[rt][3] * inv);
                pwv[rt][0] = c0.u; pwv[rt][1] = c1.u;
            }
            // redistribute C-frag -> B-frag layout: word t of kt comes from lane gs*16+li,
            // tile rt_s = 2kt + rsel, pair h2 = t&1, gs = 2*(gt&1) + (t>>1)
            unsigned bfw[2][4];
            #pragma unroll
            for (int kt = 0; kt < 2; kt++){
                #pragma unroll
                for (int t = 0; t < 4; t++){
                    int gs   = ((gt_ & 1) << 1) + (t >> 1);
                    int addr = (((gs << 4) + li_) << 2);
                    int w0 = __builtin_amdgcn_ds_bpermute(addr, (int)pwv[2*kt + 0][t & 1]);
                    int w1 = __builtin_amdgcn_ds_bpermute(addr, (int)pwv[2*kt + 1][t & 1]);
                    bfw[kt][t] = rsel ? (unsigned)w1 : (unsigned)w0;
                }
            }
            union { unsigned u[4]; bf16x8 v; } pb0, pb1;
            #pragma unroll
            for (int t = 0; t < 4; t++){ pb0.u[t] = bfw[0][t]; pb1.u[t] = bfw[1][t]; }
            __builtin_amdgcn_s_setprio(1);
            #pragma unroll
            for (int dt = 0; dt < 2; dt++){
                f32x4 o = {0.f,0.f,0.f,0.f};
                bf16x8 a0 = *(const bf16x8*)&Vt[h*32 + dt*16 + li_][gt_*8];
                bf16x8 a1 = *(const bf16x8*)&Vt[h*32 + dt*16 + li_][32 + gt_*8];
                o = MFMA16(a0, pb0.v, o);
                o = MFMA16(a1, pb1.v, o);
                ov[ui][dt] = o;
            }
            __builtin_amdgcn_s_setprio(0);
        }
        __syncthreads();   // all Qs reads done
        #pragma unroll
        for (int ui = 0; ui < 3; ui++){
            const int u = w * 3 + ui;
            const int h = u >> 2, qct = u & 3;
            const int tok = qct * 16 + li_;
            #pragma unroll
            for (int dt = 0; dt < 2; dt++){
                int cb = h * 32 + dt * 16 + (gt_ << 2);
                bf16x4 t;
                #pragma unroll
                for (int r = 0; r < 4; r++) t[r] = (__bf16)ov[ui][dt][r];
                *(bf16x4*)&Qs[tok][cb] = t;
            }
        }
        __syncthreads();
        {   // outproj: Y^T = Wp^T @ out^T ; += into d_out (y = sc + attn)
            const int ct = w & 3, rh = w >> 2;
            const int ql = ct * 16 + (lane & 15);
            const int ft = ((b * 32 + 8 * sw_ + qt) * 64 + 8 * hw_ + (ql >> 3)) * 64 + 8 * ww_ + (ql & 7);
            bf16x8 bfr[6];
            #pragma unroll
            for (int kt = 0; kt < 6; kt++) bfr[kt] = *(const bf16x8*)&Qs[ql][kt*32 + (lane>>4)*8];
            #pragma unroll
            for (int i = 0; i < 3; i++){
                int rt = rh * 3 + i;
                f32x4 acc = {0.f,0.f,0.f,0.f};
                #pragma unroll
                for (int kt = 0; kt < 6; kt++) acc = MFMA16(afrag(wsw + WP_OFF, 6, kt, rt, lane), bfr[kt], acc);
                int cb = rt * 16 + ((lane >> 4) << 2);
                float4 b4 = *(const float4*)&bpj[cb];
                float4 old = *(const float4*)&yout[ft * 96 + cb];
                float4 res;
                res.x = old.x + acc[0] + b4.x;
                res.y = old.y + acc[1] + b4.y;
                res.z = old.z + acc[2] + b4.z;
                res.w = old.w + acc[3] + b4.w;
                *(float4*)&yout[ft * 96 + cb] = res;
            }
        }
        __syncthreads();   // before next qt overwrites Qs
    }
}

// ---------------- MLP (MFMA): d_out = y + W2(gelu(W1 ln(y)+b1))+b2, in place ----------------
__global__ __launch_bounds__(512) void k_mlp(const float* __restrict__ y,
    const float* __restrict__ g2, const float* __restrict__ b2v,
    const __bf16* __restrict__ wsw, const float* __restrict__ b1m,
    const float* __restrict__ b2m, float* __restrict__ outp){
    __shared__ __bf16 yln[64][104];
    __shared__ __bf16 hsm[64][392];
    __shared__ __bf16 ybf[64][96];    // raw y stash for residual (saves 101MB global re-read)
    const int tid = threadIdx.x, lane = tid & 63, w = tid >> 6;
    const int t0 = blockIdx.x * 64;
    {   // LN stage
        int row = tid >> 3, sub = tid & 7;
        const float* yp = y + (t0 + row) * 96 + sub * 12;
        float v[12]; float s = 0.f, ss = 0.f;
        #pragma unroll
        for (int i = 0; i < 3; i++){
            float4 t = ((const float4*)yp)[i];
            v[4*i] = t.x; v[4*i+1] = t.y; v[4*i+2] = t.z; v[4*i+3] = t.w;
            s += t.x + t.y + t.z + t.w;
            ss += t.x*t.x + t.y*t.y + t.z*t.z + t.w*t.w;
        }
        #pragma unroll
        for (int i = 0; i < 3; i++){
            bf16x4 t;
            #pragma unroll
            for (int jj = 0; jj < 4; jj++) t[jj] = (__bf16)v[4*i+jj];
            *(bf16x4*)&ybf[row][sub*12 + 4*i] = t;
        }
        #pragma unroll
        for (int m = 1; m < 8; m <<= 1){ s += __shfl_xor(s, m); ss += __shfl_xor(ss, m); }
        float mu = s * (1.f/96.f), var = ss * (1.f/96.f) - mu*mu, rs = rsqrtf(var + 1e-5f);
        #pragma unroll
        for (int i = 0; i < 3; i++){
            bf16x4 t;
            #pragma unroll
            for (int jj = 0; jj < 4; jj++){
                int c = sub*12 + 4*i + jj;
                t[jj] = (__bf16)((v[4*i+jj] - mu) * rs * g2[c] + b2v[c]);
            }
            *(bf16x4*)&yln[row][sub*12 + 4*i] = t;
        }
    }
    __syncthreads();
    const int ct = w & 3, rh = w >> 2;
    const int tok = ct * 16 + (lane & 15);
    {   // GEMM1: h^T = W1^T @ yln^T, gelu -> hsm row-major
        bf16x8 bfr[3];
        #pragma unroll
        for (int kt = 0; kt < 3; kt++) bfr[kt] = *(const bf16x8*)&yln[tok][kt*32 + (lane>>4)*8];
        #pragma unroll
        for (int i = 0; i < 12; i++){
            int rt = rh * 12 + i;
            f32x4 acc = {0.f,0.f,0.f,0.f};
            #pragma unroll
            for (int kt = 0; kt < 3; kt++) acc = MFMA16(afrag(wsw + W1_OFF, 24, kt, rt, lane), bfr[kt], acc);
            int cb = rt * 16 + ((lane >> 4) << 2);
            float4 b4 = *(const float4*)&b1m[cb];
            bf16x4 t;
            t[0] = (__bf16)gelu_exact(acc[0] + b4.x);
            t[1] = (__bf16)gelu_exact(acc[1] + b4.y);
            t[2] = (__bf16)gelu_exact(acc[2] + b4.z);
            t[3] = (__bf16)gelu_exact(acc[3] + b4.w);
            *(bf16x4*)&hsm[tok][cb] = t;
        }
    }
    __syncthreads();
    {   // GEMM2: o^T = W2^T @ h^T ; residual add from LDS stash, in-place
        bf16x8 bfr[12];
        #pragma unroll
        for (int kt = 0; kt < 12; kt++) bfr[kt] = *(const bf16x8*)&hsm[tok][kt*32 + (lane>>4)*8];
        #pragma unroll
        for (int i = 0; i < 3; i++){
            int rt = rh * 3 + i;
            f32x4 acc = {0.f,0.f,0.f,0.f};
            #pragma unroll
            for (int kt = 0; kt < 12; kt++) acc = MFMA16(afrag(wsw + W2_OFF, 6, kt, rt, lane), bfr[kt], acc);
            int cb = rt * 16 + ((lane >> 4) << 2);
            float4 b4 = *(const float4*)&b2m[cb];
            bf16x4 yv = *(const bf16x4*)&ybf[tok][cb];
            float4 res;
            res.x = (float)yv[0] + acc[0] + b4.x;
            res.y = (float)yv[1] + acc[1] + b4.y;
            res.z = (float)yv[2] + acc[2] + b4.z;
            res.w = (float)yv[3] + acc[3] + b4.w;
            *(float4*)&outp[(t0 + tok) * 96 + cb] = res;
        }
    }
}

extern "C" void kernel_launch(void* const* d_in, const int* in_sizes, int n_in,
                              void* d_out, int out_size, void* d_ws, size_t ws_size,
                              hipStream_t stream){
    const float* x    = (const float*)d_in[0];
    const float* xd   = (const float*)d_in[1];
    const float* g1   = (const float*)d_in[2];
    const float* b1v  = (const float*)d_in[3];
    const float* Wkv  = (const float*)d_in[4];
    const float* bkv  = (const float*)d_in[5];
    const float* Wq   = (const float*)d_in[6];
    const float* bq   = (const float*)d_in[7];
    const float* Wp   = (const float*)d_in[8];
    const float* bpj  = (const float*)d_in[9];
    const float* btab = (const float*)d_in[10];
    const float* eg   = (const float*)d_in[11];
    const float* eb   = (const float*)d_in[12];
    const float* dw   = (const float*)d_in[13];
    const float* db   = (const float*)d_in[14];
    const float* g2   = (const float*)d_in[15];
    const float* b2v  = (const float*)d_in[16];
    const float* W1   = (const float*)d_in[17];
    const float* b1m  = (const float*)d_in[18];
    const float* W2   = (const float*)d_in[19];
    const float* b2m  = (const float*)d_in[20];
    (void)in_sizes; (void)n_in; (void)out_size; (void)ws_size;

    float*   out  = (float*)d_out;
    float*   bias = (float*)d_ws;
    __bf16*  wsw  = (__bf16*)((char*)d_ws + BIAS_BYTES);

    k_prep  <<<2064, 256, 0, stream>>>(btab, Wkv, Wq, Wp, dw, W1, W2, bias, wsw);
    k_deconv<<<512, 512, 0, stream>>>(x, eg, eb, wsw, db, out);
    k_attn  <<<512, 512, 0, stream>>>(x, xd, g1, b1v, bkv, bq, bpj, wsw, bias, out);
    k_mlp   <<<4096, 512, 0, stream>>>(out, g2, b2v, wsw, b1m, b2m, out);
}